// Round 6
// baseline (734.855 us; speedup 1.0000x reference)
//
#include <hip/hip_runtime.h>
#include <hip/hip_bf16.h>
#include <cstdint>
#include <cstddef>

#define IN_DIM 512
#define HID 256
#define OUTD 64
#define NEG_SLOPE 0.2f

typedef __attribute__((ext_vector_type(8))) __bf16 bfrag_t;      // MFMA A/B operand
typedef __attribute__((ext_vector_type(4))) float facc_t;        // MFMA C/D
typedef __attribute__((ext_vector_type(4))) unsigned int u32x4;  // 16B copies

__device__ __forceinline__ float bf2f(unsigned short u) {
  return __uint_as_float(((unsigned int)u) << 16);
}
__device__ __forceinline__ unsigned short f2bf(float f) {
  unsigned int x = __float_as_uint(f);
  x = (x + 0x7FFFu + ((x >> 16) & 1u)) >> 16;  // RNE
  return (unsigned short)x;
}

// async global->LDS 16B/lane; LDS dst is wave-uniform base + lane*16 [m97/m104]
#define GLOAD_LDS16(g, l)                                              \
  __builtin_amdgcn_global_load_lds(                                    \
      (const __attribute__((address_space(1))) void*)(g),              \
      (__attribute__((address_space(3))) void*)(l), 16, 0, 0)

// ---------------- MFMA GEMM, B^T layout: C[m,n] = sum_k A[m,k] * B[n,k] ----------------
// Used only for conv4 now (c32 output). BN=128 is the measured-good point (R4: BN=256
// acc[4][8] register collapse -> 96us @5% MfmaUtil).
template <int BM, int BN>
__global__ __launch_bounds__(256) void gemm_bt(const unsigned short* __restrict__ A,
                                               const unsigned short* __restrict__ B,
                                               float* __restrict__ C,
                                               int M, int N, int K) {
  constexpr int FM = BM / 32, FN = BN / 32;
  constexpr int RT = BM + BN;
  __shared__ __align__(16) unsigned short lds[RT * 32];

  const int bm0 = blockIdx.x * BM;
  const int bn0 = blockIdx.y * BN;
  const int tid = threadIdx.x;
  const int lane = tid & 63;
  const int wave = tid >> 6;
  const int wrow = (wave >> 1) * (BM / 2);
  const int wcol = (wave & 1) * (BN / 2);
  const int lr = lane & 15;
  const int quad = lane >> 4;
  const int swz = (quad ^ (lr & 3)) << 3;  // swizzled 8-elem slot within 32-elem row

  facc_t acc[FM][FN];
#pragma unroll
  for (int i = 0; i < FM; ++i)
#pragma unroll
    for (int j = 0; j < FN; ++j) acc[i][j] = (facc_t){0.f, 0.f, 0.f, 0.f};

  for (int k0 = 0; k0 < K; k0 += 32) {
    __syncthreads();  // previous iter's ds_reads done before overwrite
#pragma unroll
    for (int t = wave; t < RT / 16; t += 4) {
      const int r0 = t * 16;  // uniform per instr; A/B split is 16-row aligned
      const int row = r0 + (lane >> 2);
      const int seg = (lane & 3) ^ (row & 3);
      const unsigned short* g;
      if (r0 < BM) {
        int gm = bm0 + row;
        if (gm >= M) gm = M - 1;  // clamp; stores guarded in epilogue
        g = A + (size_t)gm * K + k0 + seg * 8;
      } else {
        g = B + (size_t)(bn0 + row - BM) * K + k0 + seg * 8;
      }
      GLOAD_LDS16(g, lds + t * 512);
    }
    __syncthreads();  // compiler drains vmcnt(0) before barrier

    bfrag_t a[FM], b[FN];
#pragma unroll
    for (int i = 0; i < FM; ++i)
      a[i] = *(const bfrag_t*)&lds[(wrow + i * 16 + lr) * 32 + swz];
#pragma unroll
    for (int j = 0; j < FN; ++j)
      b[j] = *(const bfrag_t*)&lds[(BM + wcol + j * 16 + lr) * 32 + swz];
#pragma unroll
    for (int i = 0; i < FM; ++i)
#pragma unroll
      for (int j = 0; j < FN; ++j)
        acc[i][j] = __builtin_amdgcn_mfma_f32_16x16x32_bf16(a[i], b[j], acc[i][j], 0, 0, 0);
  }

  // C/D layout: col=lane&15, row=quad*4+reg  [verified m89/m91]
#pragma unroll
  for (int i = 0; i < FM; ++i)
#pragma unroll
    for (int r = 0; r < 4; ++r) {
      const int grow = bm0 + wrow + i * 16 + quad * 4 + r;
      if (grow < M) {
#pragma unroll
        for (int j = 0; j < FN; ++j)
          C[(size_t)grow * N + bn0 + wcol + j * 16 + lr] = acc[i][j][r];
      }
    }
}

// ---- conv1: A fp32 (converted during reg-staging), BN=128, att-dots fused into the
// epilogue via 16-lane shfl reduce + atomicAdd partials (as_/ad_ pre-zeroed).
template <int BM, int BN>
__global__ __launch_bounds__(256) void gemm_a32_bt_att(const float* __restrict__ A,
                                                       const unsigned short* __restrict__ B,
                                                       unsigned short* __restrict__ C,
                                                       const float* __restrict__ att_s,
                                                       const float* __restrict__ att_d,
                                                       float* __restrict__ as_,
                                                       float* __restrict__ ad_,
                                                       int M, int N, int K) {
  constexpr int FM = BM / 32, FN = BN / 32;
  constexpr int RT = BM + BN;
  __shared__ __align__(16) unsigned short lds[RT * 32];

  const int bm0 = blockIdx.x * BM;
  const int bn0 = blockIdx.y * BN;
  const int tid = threadIdx.x;
  const int lane = tid & 63;
  const int wave = tid >> 6;
  const int wrow = (wave >> 1) * (BM / 2);
  const int wcol = (wave & 1) * (BN / 2);
  const int lr = lane & 15;
  const int quad = lane >> 4;
  const int swz = (quad ^ (lr & 3)) << 3;

  const int arow0 = tid >> 2;  // A staging: rows 0..63 (x2 halves)
  const int aseg = tid & 3;

  facc_t acc[FM][FN];
#pragma unroll
  for (int i = 0; i < FM; ++i)
#pragma unroll
    for (int j = 0; j < FN; ++j) acc[i][j] = (facc_t){0.f, 0.f, 0.f, 0.f};

  for (int k0 = 0; k0 < K; k0 += 32) {
    __syncthreads();
    // B rows -> lds rows [BM, BM+BN) via async DMA (pre-swizzled source)
#pragma unroll
    for (int t = wave; t < BN / 16; t += 4) {
      const int lr0 = BM + t * 16;
      const int row = lr0 + (lane >> 2);
      const int seg = (lane & 3) ^ (row & 3);
      const unsigned short* g = B + (size_t)(bn0 + t * 16 + (lane >> 2)) * K + k0 + seg * 8;
      GLOAD_LDS16(g, lds + lr0 * 32);
    }
    // A rows via regs: load 8 fp32, cvt bf16x8, ds_write_b128 to swizzled slot
#pragma unroll
    for (int h = 0; h < 2; ++h) {
      const int row = arow0 + h * (BM / 2);
      int gm = bm0 + row;
      if (gm >= M) gm = M - 1;
      const float* g = A + (size_t)gm * K + k0 + aseg * 8;
      const float4 fa = ((const float4*)g)[0];
      const float4 fb = ((const float4*)g)[1];
      u32x4 pk;
      pk.x = (unsigned int)f2bf(fa.x) | ((unsigned int)f2bf(fa.y) << 16);
      pk.y = (unsigned int)f2bf(fa.z) | ((unsigned int)f2bf(fa.w) << 16);
      pk.z = (unsigned int)f2bf(fb.x) | ((unsigned int)f2bf(fb.y) << 16);
      pk.w = (unsigned int)f2bf(fb.z) | ((unsigned int)f2bf(fb.w) << 16);
      *(u32x4*)&lds[row * 32 + ((aseg ^ (row & 3)) << 3)] = pk;
    }
    __syncthreads();

    bfrag_t a[FM], b[FN];
#pragma unroll
    for (int i = 0; i < FM; ++i)
      a[i] = *(const bfrag_t*)&lds[(wrow + i * 16 + lr) * 32 + swz];
#pragma unroll
    for (int j = 0; j < FN; ++j)
      b[j] = *(const bfrag_t*)&lds[(BM + wcol + j * 16 + lr) * 32 + swz];
#pragma unroll
    for (int i = 0; i < FM; ++i)
#pragma unroll
      for (int j = 0; j < FN; ++j)
        acc[i][j] = __builtin_amdgcn_mfma_f32_16x16x32_bf16(a[i], b[j], acc[i][j], 0, 0, 0);
  }

  float av_s[FN], av_d[FN];
#pragma unroll
  for (int j = 0; j < FN; ++j) {
    av_s[j] = att_s[bn0 + wcol + j * 16 + lr];
    av_d[j] = att_d[bn0 + wcol + j * 16 + lr];
  }
#pragma unroll
  for (int i = 0; i < FM; ++i)
#pragma unroll
    for (int r = 0; r < 4; ++r) {
      const int grow = bm0 + wrow + i * 16 + quad * 4 + r;
      float ps = 0.f, pd = 0.f;
#pragma unroll
      for (int j = 0; j < FN; ++j) {
        const float v = acc[i][j][r];
        ps += v * av_s[j];
        pd += v * av_d[j];
        if (grow < M) C[(size_t)grow * N + bn0 + wcol + j * 16 + lr] = f2bf(v);
      }
      // reduce over the 16 lanes (lr) sharing this row within the wave-half
      ps += __shfl_xor(ps, 1); ps += __shfl_xor(ps, 2);
      ps += __shfl_xor(ps, 4); ps += __shfl_xor(ps, 8);
      pd += __shfl_xor(pd, 1); pd += __shfl_xor(pd, 2);
      pd += __shfl_xor(pd, 4); pd += __shfl_xor(pd, 8);
      if (lr == 0 && grow < M) {
        atomicAdd(&as_[grow], ps);
        atomicAdd(&ad_[grow], pd);
      }
    }
}

// ---------------- weight conversions + zero-init (one launch) ----------------
__global__ void cvt_weights(const float* __restrict__ W1, const float* __restrict__ W2,
                            unsigned short* __restrict__ W1T, unsigned short* __restrict__ W1b,
                            unsigned short* __restrict__ W2T, unsigned short* __restrict__ W2b,
                            float* __restrict__ as_, float* __restrict__ ad_,
                            int* __restrict__ deg, int n) {
  const int idx = blockIdx.x * 256 + threadIdx.x;
  if (idx < IN_DIM * HID) {
    const unsigned short b = f2bf(W1[idx]);
    W1b[idx] = b;
    const int r = idx >> 8, c = idx & 255;  // W1 row-major [512,256]
    W1T[(size_t)c * IN_DIM + r] = b;
  }
  if (idx < HID * OUTD) {
    const unsigned short b = f2bf(W2[idx]);
    W2b[idx] = b;
    const int r = idx >> 6, c = idx & 63;  // W2 row-major [256,64]
    W2T[(size_t)c * HID + r] = b;
  }
  if (idx < n) {
    as_[idx] = 0.f;
    ad_[idx] = 0.f;
    deg[idx] = 0;
  }
}

// degree count only (exp recomputed in edge_scatter; no eexp array)
__global__ void edge_deg(const int* __restrict__ src, const int* __restrict__ dst,
                         int* __restrict__ deg, int E, int n) {
  const int e = blockIdx.x * 256 + threadIdx.x;
  if (e >= E) return;
  const int s = src[e], d = dst[e];
  if ((unsigned)s >= (unsigned)n || (unsigned)d >= (unsigned)n) return;
  atomicAdd(&deg[d], 1);
}

// ---------------- hierarchical scan ----------------
__global__ __launch_bounds__(256) void scan_reduce(const int* __restrict__ deg,
                                                   int* __restrict__ bsum, int n) {
  __shared__ int ws4[4];
  const int tid = threadIdx.x, lane = tid & 63, wid = tid >> 6;
  const int base = blockIdx.x * 2048 + tid * 8;
  int s = 0;
#pragma unroll
  for (int j = 0; j < 8; ++j) {
    const int i = base + j;
    if (i < n) s += deg[i];
  }
  for (int off = 32; off > 0; off >>= 1) s += __shfl_down(s, off);
  if (lane == 0) ws4[wid] = s;
  __syncthreads();
  if (tid == 0) bsum[blockIdx.x] = ws4[0] + ws4[1] + ws4[2] + ws4[3];
}

__global__ __launch_bounds__(256) void scan_final(const int* __restrict__ deg,
                                                  const int* __restrict__ bsum,
                                                  int* __restrict__ row_ptr,
                                                  int* __restrict__ cursor, int n) {
  __shared__ int wsum[4];
  __shared__ int blockoff;
  const int tid = threadIdx.x, lane = tid & 63, wid = tid >> 6;
  if (wid == 0) {
    int v = (lane < blockIdx.x) ? bsum[lane] : 0;
    for (int off = 32; off > 0; off >>= 1) v += __shfl_down(v, off);
    if (lane == 0) blockoff = v;
  }
  const int base = blockIdx.x * 2048 + tid * 8;
  int v[8], s = 0;
#pragma unroll
  for (int j = 0; j < 8; ++j) {
    const int i = base + j;
    v[j] = (i < n) ? deg[i] : 0;
    s += v[j];
  }
  int ws = s;
  for (int off = 1; off < 64; off <<= 1) {
    const int t = __shfl_up(ws, off);
    if (lane >= off) ws += t;
  }
  if (lane == 63) wsum[wid] = ws;
  __syncthreads();
  int woff = 0;
  for (int w_ = 0; w_ < wid; ++w_) woff += wsum[w_];
  int run = blockoff + woff + (ws - s);
#pragma unroll
  for (int j = 0; j < 8; ++j) {
    const int i = base + j;
    if (i < n) {
      cursor[i] = run;
      row_ptr[i + 1] = run + v[j];
    }
    run += v[j];
  }
  if (blockIdx.x == 0 && tid == 0) row_ptr[0] = 0;
}

// CSR entry interleaved: .x = src node, .y = exp-weight bits. Recomputes the
// logit+exp inline (as_/ad_ gathers are L2 hits; deletes the eexp array).
__global__ void edge_scatter(const int* __restrict__ src, const int* __restrict__ dst,
                             const float* __restrict__ as_, const float* __restrict__ ad_,
                             int* __restrict__ cursor, int2* __restrict__ csr, int E, int n) {
  const int e = blockIdx.x * 256 + threadIdx.x;
  if (e >= E) return;
  const int s = src[e], d = dst[e];
  if ((unsigned)s >= (unsigned)n || (unsigned)d >= (unsigned)n) return;
  float l = as_[s] + ad_[d];
  l = l > 0.f ? l : NEG_SLOPE * l;
  const float ex = expf(fminf(l, 60.f));
  const int pos = atomicAdd(&cursor[d], 1);
  int2 c;
  c.x = s;
  c.y = __float_as_int(ex);
  csr[pos] = c;
}

// conv1-propagate + elu + FUSED conv2 (h1 never hits global memory):
// h1 = elu(prop(hp1)) held in LDS; h2[n] = h1 . W2T[n] computed per-lane;
// writes h2 fp32 (output) and h2b bf16. W2T is L1-resident (32 KB).
__global__ __launch_bounds__(256) void gat_prop256_fc(const unsigned short* __restrict__ hpre,
                                                      const int* __restrict__ row_ptr,
                                                      const int2* __restrict__ csr,
                                                      const unsigned short* __restrict__ W2T,
                                                      float* __restrict__ h2out,
                                                      unsigned short* __restrict__ h2b,
                                                      int n) {
  __shared__ float h1row[4][256];
  const int nib = threadIdx.x >> 6;
  const int node = blockIdx.x * 4 + nib;
  if (node >= n) return;
  const int lane = threadIdx.x & 63;
  const int half = lane >> 5;
  const int lh = lane & 31;
  const int beg = row_ptr[node], end = row_ptr[node + 1];
  const int deg = end - beg;
  const unsigned short* base = hpre + (lh << 3);
  float a[8] = {0.f, 0.f, 0.f, 0.f, 0.f, 0.f, 0.f, 0.f};
  float wsum = 0.f;

  int cs = 0;
  float cw = 0.f;
  if (lane < deg) {
    const int2 t = csr[beg + lane];
    cs = t.x;
    cw = __int_as_float(t.y);
  }
  const int dmain = deg < 64 ? deg : 64;
  for (int j0 = 0; j0 < dmain; j0 += 16) {
#pragma unroll
    for (int u = 0; u < 8; ++u) {
      const int j = j0 + 2 * u + half;
      const bool valid = j < dmain;
      const int jj = valid ? j : 0;
      const int s = __shfl(cs, jj);
      float w = __shfl(cw, jj);
      w = valid ? w : 0.f;
      const u32x4 v = *(const u32x4*)(base + (size_t)s * HID);
      wsum += w;
      a[0] += w * bf2f((unsigned short)(v.x & 0xffffu));
      a[1] += w * bf2f((unsigned short)(v.x >> 16));
      a[2] += w * bf2f((unsigned short)(v.y & 0xffffu));
      a[3] += w * bf2f((unsigned short)(v.y >> 16));
      a[4] += w * bf2f((unsigned short)(v.z & 0xffffu));
      a[5] += w * bf2f((unsigned short)(v.z >> 16));
      a[6] += w * bf2f((unsigned short)(v.w & 0xffffu));
      a[7] += w * bf2f((unsigned short)(v.w >> 16));
    }
  }
  // rare tail: deg > 64
  for (int e = beg + 64; e < end; e += 2) {
    const int e2 = e + half;
    if (e2 < end) {
      const int2 c = csr[e2];
      const float w = __int_as_float(c.y);
      const u32x4 v = *(const u32x4*)(base + (size_t)c.x * HID);
      wsum += w;
      a[0] += w * bf2f((unsigned short)(v.x & 0xffffu));
      a[1] += w * bf2f((unsigned short)(v.x >> 16));
      a[2] += w * bf2f((unsigned short)(v.y & 0xffffu));
      a[3] += w * bf2f((unsigned short)(v.y >> 16));
      a[4] += w * bf2f((unsigned short)(v.z & 0xffffu));
      a[5] += w * bf2f((unsigned short)(v.z >> 16));
      a[6] += w * bf2f((unsigned short)(v.w & 0xffffu));
      a[7] += w * bf2f((unsigned short)(v.w >> 16));
    }
  }
#pragma unroll
  for (int i = 0; i < 8; ++i) a[i] += __shfl_xor(a[i], 32);
  wsum += __shfl_xor(wsum, 32);

  const float inv = 1.f / (wsum + 1e-16f);
#pragma unroll
  for (int i = 0; i < 8; ++i) {
    a[i] *= inv;
    a[i] = a[i] > 0.f ? a[i] : (expf(a[i]) - 1.f);
  }
  if (half == 0) {
#pragma unroll
    for (int i = 0; i < 8; ++i) h1row[nib][lh * 8 + i] = a[i];
  }
  // same-wave LDS write->read; compiler inserts lgkmcnt wait. No barrier needed
  // (each wave touches only its own node slot).
  const u32x4* wrow = (const u32x4*)(W2T + (size_t)lane * HID);
  float h2 = 0.f;
#pragma unroll
  for (int c8 = 0; c8 < 32; ++c8) {
    const u32x4 wv = wrow[c8];
    const float4 h0 = *(const float4*)&h1row[nib][c8 * 8];
    const float4 h1_ = *(const float4*)&h1row[nib][c8 * 8 + 4];
    h2 += h0.x * bf2f((unsigned short)(wv.x & 0xffffu))
        + h0.y * bf2f((unsigned short)(wv.x >> 16))
        + h0.z * bf2f((unsigned short)(wv.y & 0xffffu))
        + h0.w * bf2f((unsigned short)(wv.y >> 16))
        + h1_.x * bf2f((unsigned short)(wv.z & 0xffffu))
        + h1_.y * bf2f((unsigned short)(wv.z >> 16))
        + h1_.z * bf2f((unsigned short)(wv.w & 0xffffu))
        + h1_.w * bf2f((unsigned short)(wv.w >> 16));
  }
  h2out[(size_t)node * OUTD + lane] = h2;
  h2b[(size_t)node * OUTD + lane] = f2bf(h2);
}

// conv3-propagate (64-dim) + FUSED conv3' matvec + elu: h3[c] = elu(g2 . W2b[c]),
// lane computes c = 4*lane..4*lane+3, writes one uint2 (4 bf16) coalesced.
__global__ __launch_bounds__(256) void gat_prop64_fc(const unsigned short* __restrict__ hpre,
                                                     const int* __restrict__ row_ptr,
                                                     const int2* __restrict__ csr,
                                                     const unsigned short* __restrict__ W2b,
                                                     unsigned short* __restrict__ h3out,
                                                     int n) {
  __shared__ float g2row[4][64];
  const int nib = threadIdx.x >> 6;
  const int node = blockIdx.x * 4 + nib;
  if (node >= n) return;
  const int lane = threadIdx.x & 63;
  const int quad = lane >> 4;
  const int lr = lane & 15;
  const int beg = row_ptr[node], end = row_ptr[node + 1];
  const int deg = end - beg;
  const unsigned short* base = hpre + (lr << 2);
  float a0 = 0.f, a1 = 0.f, a2 = 0.f, a3 = 0.f, wsum = 0.f;

  int cs = 0;
  float cw = 0.f;
  if (lane < deg) {
    const int2 t = csr[beg + lane];
    cs = t.x;
    cw = __int_as_float(t.y);
  }
  const int dmain = deg < 64 ? deg : 64;
  for (int j0 = 0; j0 < dmain; j0 += 16) {
#pragma unroll
    for (int u = 0; u < 4; ++u) {
      const int j = j0 + 4 * u + quad;
      const bool valid = j < dmain;
      const int jj = valid ? j : 0;
      const int s = __shfl(cs, jj);
      float w = __shfl(cw, jj);
      w = valid ? w : 0.f;
      const uint2 v = *(const uint2*)(base + (size_t)s * OUTD);
      wsum += w;
      a0 += w * bf2f((unsigned short)(v.x & 0xffffu));
      a1 += w * bf2f((unsigned short)(v.x >> 16));
      a2 += w * bf2f((unsigned short)(v.y & 0xffffu));
      a3 += w * bf2f((unsigned short)(v.y >> 16));
    }
  }
  for (int e = beg + 64; e < end; e += 4) {
    const int e2 = e + quad;
    if (e2 < end) {
      const int2 c = csr[e2];
      const float w = __int_as_float(c.y);
      const uint2 v = *(const uint2*)(base + (size_t)c.x * OUTD);
      wsum += w;
      a0 += w * bf2f((unsigned short)(v.x & 0xffffu));
      a1 += w * bf2f((unsigned short)(v.x >> 16));
      a2 += w * bf2f((unsigned short)(v.y & 0xffffu));
      a3 += w * bf2f((unsigned short)(v.y >> 16));
    }
  }
  a0 += __shfl_xor(a0, 16); a0 += __shfl_xor(a0, 32);
  a1 += __shfl_xor(a1, 16); a1 += __shfl_xor(a1, 32);
  a2 += __shfl_xor(a2, 16); a2 += __shfl_xor(a2, 32);
  a3 += __shfl_xor(a3, 16); a3 += __shfl_xor(a3, 32);
  wsum += __shfl_xor(wsum, 16); wsum += __shfl_xor(wsum, 32);

  const float inv = 1.f / (wsum + 1e-16f);
  if (quad == 0) {
    g2row[nib][lr * 4 + 0] = a0 * inv;
    g2row[nib][lr * 4 + 1] = a1 * inv;
    g2row[nib][lr * 4 + 2] = a2 * inv;
    g2row[nib][lr * 4 + 3] = a3 * inv;
  }
  // matvec: 4 output rows per lane, W2b rows 4*lane..4*lane+3 (L1-resident)
  const u32x4* wr0 = (const u32x4*)(W2b + (size_t)(4 * lane + 0) * OUTD);
  const u32x4* wr1 = (const u32x4*)(W2b + (size_t)(4 * lane + 1) * OUTD);
  const u32x4* wr2 = (const u32x4*)(W2b + (size_t)(4 * lane + 2) * OUTD);
  const u32x4* wr3 = (const u32x4*)(W2b + (size_t)(4 * lane + 3) * OUTD);
  float o0 = 0.f, o1 = 0.f, o2 = 0.f, o3 = 0.f;
#pragma unroll
  for (int n8 = 0; n8 < 8; ++n8) {
    const float4 g0 = *(const float4*)&g2row[nib][n8 * 8];
    const float4 g1 = *(const float4*)&g2row[nib][n8 * 8 + 4];
    const u32x4 w0 = wr0[n8];
    const u32x4 w1 = wr1[n8];
    const u32x4 w2 = wr2[n8];
    const u32x4 w3 = wr3[n8];
#define DOT8(wv)                                                           \
  (g0.x * bf2f((unsigned short)(wv.x & 0xffffu)) +                         \
   g0.y * bf2f((unsigned short)(wv.x >> 16)) +                             \
   g0.z * bf2f((unsigned short)(wv.y & 0xffffu)) +                         \
   g0.w * bf2f((unsigned short)(wv.y >> 16)) +                             \
   g1.x * bf2f((unsigned short)(wv.z & 0xffffu)) +                         \
   g1.y * bf2f((unsigned short)(wv.z >> 16)) +                             \
   g1.z * bf2f((unsigned short)(wv.w & 0xffffu)) +                         \
   g1.w * bf2f((unsigned short)(wv.w >> 16)))
    o0 += DOT8(w0);
    o1 += DOT8(w1);
    o2 += DOT8(w2);
    o3 += DOT8(w3);
#undef DOT8
  }
  o0 = o0 > 0.f ? o0 : (expf(o0) - 1.f);
  o1 = o1 > 0.f ? o1 : (expf(o1) - 1.f);
  o2 = o2 > 0.f ? o2 : (expf(o2) - 1.f);
  o3 = o3 > 0.f ? o3 : (expf(o3) - 1.f);
  uint2 o;
  o.x = (unsigned int)f2bf(o0) | ((unsigned int)f2bf(o1) << 16);
  o.y = (unsigned int)f2bf(o2) | ((unsigned int)f2bf(o3) << 16);
  *(uint2*)(h3out + (size_t)node * HID + 4 * lane) = o;
}

extern "C" void kernel_launch(void* const* d_in, const int* in_sizes, int n_in,
                              void* d_out, int out_size, void* d_ws, size_t ws_size,
                              hipStream_t stream) {
  const float* feat = (const float*)d_in[0];   // [N, 512] fp32
  const float* W1 = (const float*)d_in[1];     // [512, 256] fp32
  const float* W2 = (const float*)d_in[2];     // [256, 64] fp32
  const float* att_s = (const float*)d_in[3];  // [256] fp32
  const float* att_d = (const float*)d_in[4];  // [256] fp32
  const int* ei = (const int*)d_in[5];         // [2, E] int32
  const int N = in_sizes[0] / IN_DIM;          // 50000
  const int E = in_sizes[5] / 2;               // 600000
  const int* src = ei;
  const int* dst = ei + E;
  float* outf = (float*)d_out;  // h2 [N,64] fp32 ++ h4 [N,512] fp32

  // Park hp1 in the not-yet-written h4 slot: hp1 dead after gat_prop256_fc;
  // conv4 writes the slot last reading only ws.
  unsigned short* hp1 = (unsigned short*)(outf + (size_t)N * OUTD);  // [N,256] bf16

  // ---- workspace carve-up (256B-aligned) ----
  char* w = (char*)d_ws;
  size_t off = 0;
  auto alloc = [&](size_t bytes) -> void* {
    void* p = w + off;
    off += (bytes + 255) & ~(size_t)255;
    return p;
  };
  unsigned short* h3 = (unsigned short*)alloc((size_t)N * HID * 2);    // h3 bf16
  unsigned short* h2b = (unsigned short*)alloc((size_t)N * OUTD * 2);  // h2 bf16
  float* a_src_v = (float*)alloc((size_t)N * 4);
  float* a_dst_v = (float*)alloc((size_t)N * 4);
  int* deg = (int*)alloc((size_t)N * 4);
  int* row_ptr = (int*)alloc((size_t)(N + 1) * 4);
  int* cursor = (int*)alloc((size_t)N * 4);
  int* bsum = (int*)alloc((size_t)64 * 4);
  int2* csr = (int2*)alloc((size_t)E * 8);
  unsigned short* W1T = (unsigned short*)alloc((size_t)IN_DIM * HID * 2);  // [256,512] bf16
  unsigned short* W1b = (unsigned short*)alloc((size_t)IN_DIM * HID * 2);  // [512,256] bf16
  unsigned short* W2T = (unsigned short*)alloc((size_t)HID * OUTD * 2);    // [64,256] bf16
  unsigned short* W2b = (unsigned short*)alloc((size_t)HID * OUTD * 2);    // [256,64] bf16

  const int EB = (E + 255) / 256;
  const int MB = (N + 127) / 128;
  const int SB = (N + 2047) / 2048;  // scan blocks (25 for N=50000; must be <= 64)

  // weight conversions + zero as_/ad_/deg (one launch, runs before everything)
  cvt_weights<<<(IN_DIM * HID + 255) / 256, 256, 0, stream>>>(W1, W2, W1T, W1b, W2T, W2b,
                                                              a_src_v, a_dst_v, deg, N);

  // conv1: hp1 = feat @ W1 (fp32 A converted in staging) + fused att-dot partials
  gemm_a32_bt_att<128, 128><<<dim3(MB, HID / 128), 256, 0, stream>>>(
      feat, W1T, hp1, att_s, att_d, a_src_v, a_dst_v, N, HID, IN_DIM);

  // edge softmax prep (tied weights shared by conv1 & conv3) + dst-CSR build
  edge_deg<<<EB, 256, 0, stream>>>(src, dst, deg, E, N);
  scan_reduce<<<SB, 256, 0, stream>>>(deg, bsum, N);
  scan_final<<<SB, 256, 0, stream>>>(deg, bsum, row_ptr, cursor, N);
  edge_scatter<<<EB, 256, 0, stream>>>(src, dst, a_src_v, a_dst_v, cursor, csr, E, N);

  // conv1 propagate + elu + fused conv2 -> h2 (fp32 out) + h2b (bf16); h1 stays in LDS
  gat_prop256_fc<<<(N + 3) / 4, 256, 0, stream>>>(hp1, row_ptr, csr, W2T, outf, h2b, N);
  // conv3 propagate (64-dim, via linearity) + fused conv3' matvec + elu -> h3
  gat_prop64_fc<<<(N + 3) / 4, 256, 0, stream>>>(h2b, row_ptr, csr, W2b, h3, N);
  // conv4: h4 = h3 @ W1^T -> outf[N*64:] (fp32)
  gemm_bt<128, 128><<<dim3(MB, IN_DIM / 128), 256, 0, stream>>>(h3, W1b,
                                                                outf + (size_t)N * OUTD,
                                                                N, IN_DIM, HID);
}